// Round 6
// baseline (4545.172 us; speedup 1.0000x reference)
//
#include <hip/hip_runtime.h>
#include <hip/hip_bf16.h>

#define BB 16
#define DEPTH 24
#define DM 192
#define DI 384
#define DS 16
#define DC 4
#define DTR 12
#define LL 320
#define NX 256
#define NZ 64
#define NT (BB * LL)
#define NC 10         // scan chunks
#define LC 32         // chunk length
#define EPSV 1e-5f

__device__ inline float siluf(float x) { return x / (1.f + __expf(-x)); }
__device__ inline float softplusf(float x) {
    return (x > 20.f) ? x : log1pf(expf(x));
}
__device__ inline float wave_sum64(float v) {
    #pragma unroll
    for (int o = 32; o > 0; o >>= 1) v += __shfl_xor(v, o);
    return v;
}

// ---------- fused add+LN + in_proj GEMM ----------
// Block: 32 tokens x 128 cols, 256 thr. GEMM phase: 4 col-waves of 32 cols;
// lane (r,c)=(lane>>3, lane&7) owns tokens {r+8i} x cols {wv*32+c+8jj}:
// 8 b128 reads per 64 FMA/lane (was 10/64). Strides 196/52 are ==4 mod 32
// -> 8-row group reads cover all 32 banks, conflict-free.
__global__ __launch_bounds__(256) void ln_gemm(const float* __restrict__ hidden,
                                               const float* __restrict__ resin,
                                               float* __restrict__ resout,
                                               const float* __restrict__ lnw,
                                               const float* __restrict__ lnb,
                                               size_t lnoff,
                                               const float* __restrict__ w,
                                               size_t woff,
                                               float* __restrict__ out,
                                               int first) {
    __shared__ float xs[32][196];
    __shared__ float ws[128][52];
    int t0 = blockIdx.x * 32;
    int j0 = blockIdx.y * 128;
    // ---- LN phase: 8-lane group per token (32 tokens / 256 threads)
    {
        int tt = threadIdx.x >> 3;
        int l8 = threadIdx.x & 7;
        size_t base = (size_t)(t0 + tt) * DM;
        float v[24];
        float s = 0.f;
        #pragma unroll
        for (int j = 0; j < 24; j++) {
            int e = l8 + 8 * j;
            float x = hidden[base + e];
            if (!first) x += resin[base + e];
            v[j] = x;
            s += x;
        }
        s += __shfl_xor(s, 1); s += __shfl_xor(s, 2); s += __shfl_xor(s, 4);
        float mu = s * (1.f / 192.f);
        float q = 0.f;
        #pragma unroll
        for (int j = 0; j < 24; j++) { float d = v[j] - mu; q += d * d; }
        q += __shfl_xor(q, 1); q += __shfl_xor(q, 2); q += __shfl_xor(q, 4);
        float inv = rsqrtf(q * (1.f / 192.f) + EPSV);
        #pragma unroll
        for (int j = 0; j < 24; j++) {
            int e = l8 + 8 * j;
            if (blockIdx.y == 0) resout[base + e] = v[j];
            xs[tt][e] = (v[j] - mu) * inv * lnw[lnoff + e] + lnb[lnoff + e];
        }
    }
    __syncthreads();
    // ---- GEMM phase
    int lane = threadIdx.x & 63;
    int wv = threadIdx.x >> 6;
    int r = lane >> 3;
    int c = lane & 7;
    float acc[4][4];
    #pragma unroll
    for (int i = 0; i < 4; i++)
        #pragma unroll
        for (int j = 0; j < 4; j++) acc[i][j] = 0.f;
    for (int kt = 0; kt < 192; kt += 48) {
        for (int idx = threadIdx.x; idx < 128 * 12; idx += 256) {
            int jj = idx / 12, kc = idx % 12;
            float4 v4 = *(const float4*)&w[woff + (size_t)(j0 + jj) * 192 + kt + kc * 4];
            *(float4*)&ws[jj][kc * 4] = v4;
        }
        __syncthreads();
        #pragma unroll 2
        for (int kk = 0; kk < 48; kk += 4) {
            float4 xv[4];
            #pragma unroll
            for (int i = 0; i < 4; i++)
                xv[i] = *(const float4*)&xs[r + 8 * i][kt + kk];
            #pragma unroll
            for (int j = 0; j < 4; j++) {
                float4 w4 = *(const float4*)&ws[wv * 32 + c + 8 * j][kk];
                #pragma unroll
                for (int i = 0; i < 4; i++)
                    acc[i][j] += xv[i].x * w4.x + xv[i].y * w4.y
                               + xv[i].z * w4.z + xv[i].w * w4.w;
            }
        }
        __syncthreads();
    }
    #pragma unroll
    for (int i = 0; i < 4; i++)
        #pragma unroll
        for (int j = 0; j < 4; j++)
            out[(size_t)(t0 + r + 8 * i) * 768 + j0 + wv * 32 + c + 8 * j] = acc[i][j];
}

// ---------- register-tiled GEMM v2: 128 thr, 32 tok x 64 cols ----------
// Lane (r,c) owns tokens {r+8i} x cols {wv*32+c+8jj}: 8 b128 per 64 FMA.
// Stride 100 == 4 mod 32 -> conflict-free 8-row group reads.
template<int K, int KT>
__global__ __launch_bounds__(128) void gemm_rt2(const float* __restrict__ x,
                                                const float* __restrict__ w,
                                                size_t woff,
                                                float* __restrict__ out, int N) {
    constexpr int KC = KT / 4;
    __shared__ float xs[32][KT + 4];
    __shared__ float ws[64][KT + 4];
    int t0 = blockIdx.x * 32;
    int j0 = blockIdx.y * 64;
    int lane = threadIdx.x & 63;
    int wv = threadIdx.x >> 6;
    int r = lane >> 3;
    int c = lane & 7;
    float acc[4][4];
    #pragma unroll
    for (int i = 0; i < 4; i++)
        #pragma unroll
        for (int j = 0; j < 4; j++) acc[i][j] = 0.f;

    for (int kt = 0; kt < K; kt += KT) {
        for (int idx = threadIdx.x; idx < 32 * KC; idx += 128) {
            int tt = idx / KC, kc = idx % KC;
            *(float4*)&xs[tt][kc * 4] =
                *(const float4*)&x[(size_t)(t0 + tt) * K + kt + kc * 4];
        }
        for (int idx = threadIdx.x; idx < 64 * KC; idx += 128) {
            int jj = idx / KC, kc = idx % KC;
            *(float4*)&ws[jj][kc * 4] =
                *(const float4*)&w[woff + (size_t)(j0 + jj) * K + kt + kc * 4];
        }
        __syncthreads();
        #pragma unroll 2
        for (int kk = 0; kk < KT; kk += 4) {
            float4 xv[4];
            #pragma unroll
            for (int i = 0; i < 4; i++)
                xv[i] = *(const float4*)&xs[r + 8 * i][kk];
            #pragma unroll
            for (int j = 0; j < 4; j++) {
                float4 w4 = *(const float4*)&ws[wv * 32 + c + 8 * j][kk];
                #pragma unroll
                for (int i = 0; i < 4; i++)
                    acc[i][j] += xv[i].x * w4.x + xv[i].y * w4.y
                               + xv[i].z * w4.z + xv[i].w * w4.w;
            }
        }
        __syncthreads();
    }
    #pragma unroll
    for (int i = 0; i < 4; i++)
        #pragma unroll
        for (int j = 0; j < 4; j++)
            out[(size_t)(t0 + r + 8 * i) * N + j0 + wv * 32 + c + 8 * j] = acc[i][j];
}

// ---------- patch embed (both images, one launch), rt2 tiling ----------
// grid: ((BB*NX + BB*NZ)/32 = 160, 3), 128 thr. blocks 0..127 -> x_img
__global__ __launch_bounds__(128) void patch_rt2(const float* __restrict__ x_img,
                                                 const float* __restrict__ z_img,
                                                 const float* __restrict__ w,
                                                 const float* __restrict__ bias,
                                                 const float* __restrict__ pos_x,
                                                 const float* __restrict__ pos_z,
                                                 float* __restrict__ hidden) {
    __shared__ float xs[32][100];
    __shared__ float ws[64][100];
    bool isx = blockIdx.x < (BB * NX / 32);
    const float* img = isx ? x_img : z_img;
    const float* pos = isx ? pos_x : pos_z;
    int side = isx ? 16 : 8;
    int tok_off = isx ? NZ : 0;
    int ntok = side * side;
    int pt0 = (isx ? blockIdx.x : blockIdx.x - BB * NX / 32) * 32;
    int j0 = blockIdx.y * 64;
    int S = side * 16;
    int lane = threadIdx.x & 63;
    int wv = threadIdx.x >> 6;
    int r = lane >> 3;
    int c = lane & 7;
    float acc[4][4];
    #pragma unroll
    for (int i = 0; i < 4; i++)
        #pragma unroll
        for (int j = 0; j < 4; j++) acc[i][j] = 0.f;

    for (int kt = 0; kt < 768; kt += 96) {
        for (int idx = threadIdx.x; idx < 32 * 24; idx += 128) {
            int tt = idx / 24, kc = idx % 24;
            int k = kt + kc * 4;
            int ci = k >> 8, p = k & 255, pi = p >> 4, pj = p & 15;
            int patch = pt0 + tt;
            int b = patch / ntok, t = patch % ntok;
            int ph = t / side, pw = t % side;
            *(float4*)&xs[tt][kc * 4] =
                *(const float4*)&img[((size_t)(b * 3 + ci) * S + ph * 16 + pi) * S
                                     + pw * 16 + pj];
        }
        for (int idx = threadIdx.x; idx < 64 * 24; idx += 128) {
            int jj = idx / 24, kc = idx % 24;
            *(float4*)&ws[jj][kc * 4] =
                *(const float4*)&w[(size_t)(j0 + jj) * 768 + kt + kc * 4];
        }
        __syncthreads();
        #pragma unroll 2
        for (int kk = 0; kk < 96; kk += 4) {
            float4 xv[4];
            #pragma unroll
            for (int i = 0; i < 4; i++)
                xv[i] = *(const float4*)&xs[r + 8 * i][kk];
            #pragma unroll
            for (int j = 0; j < 4; j++) {
                float4 w4 = *(const float4*)&ws[wv * 32 + c + 8 * j][kk];
                #pragma unroll
                for (int i = 0; i < 4; i++)
                    acc[i][j] += xv[i].x * w4.x + xv[i].y * w4.y
                               + xv[i].z * w4.z + xv[i].w * w4.w;
            }
        }
        __syncthreads();
    }
    #pragma unroll
    for (int i = 0; i < 4; i++) {
        int patch = pt0 + r + 8 * i;
        int b = patch / ntok, tk = patch % ntok;
        #pragma unroll
        for (int j = 0; j < 4; j++) {
            int col = j0 + wv * 32 + c + 8 * j;
            hidden[((size_t)b * LL + tok_off + tk) * DM + col] =
                acc[i][j] + bias[col] + pos[(size_t)tk * DM + col];
        }
    }
}

// ---------- fused conv+silu -> x_proj (reg-tiled) -> dt_proj. block = 16 tokens ----------
__global__ __launch_bounds__(256) void xpd_kernel(const float* __restrict__ xz,
                                                  const float* __restrict__ cw,
                                                  const float* __restrict__ cb,
                                                  const float* __restrict__ xpw,
                                                  const float* __restrict__ dtw,
                                                  const float* __restrict__ dtbias,
                                                  float* __restrict__ xc,
                                                  float* __restrict__ dbl,
                                                  float* __restrict__ dtbuf,
                                                  int layer) {
    __shared__ float smem[5760];
    float* xs   = smem;          // [16][52]
    float* ws   = smem + 832;    // [64][52]
    float* sdbl = smem;          // [16][48]
    float* sdtw = smem + 768;    // [384][13] -> bank (13d+r)%32, 2-way free

    int t0 = blockIdx.x * 16;
    int l0 = t0 % LL;
    int lane = threadIdx.x & 63;
    int wv = threadIdx.x >> 6;
    const float* cwl = cw  + (size_t)layer * DI * DC;
    const float* cbl = cb  + (size_t)layer * DI;
    const float* xpl = xpw + (size_t)layer * 44 * DI;
    float acc[4] = {0.f, 0.f, 0.f, 0.f};

    for (int kt = 0; kt < DI; kt += 48) {
        for (int idx = threadIdx.x; idx < 16 * 48; idx += 256) {
            int tt = idx / 48, kk = idx % 48;
            int d = kt + kk;
            float a = cbl[d];
            #pragma unroll
            for (int rr = 0; rr < 4; rr++) {
                int l = l0 + tt - 3 + rr;
                float v = (l >= 0) ? xz[(size_t)(t0 + tt - 3 + rr) * 768 + d] : 0.f;
                a += cwl[d * 4 + rr] * v;
            }
            a = siluf(a);
            xs[tt * 52 + kk] = a;
            xc[(size_t)(t0 + tt) * DI + d] = a;
        }
        for (int idx = threadIdx.x; idx < 64 * 12; idx += 256) {
            int jj = idx / 12, kc = idx % 12;
            float4 v = make_float4(0.f, 0.f, 0.f, 0.f);
            if (jj < 44)
                v = *(const float4*)&xpl[(size_t)jj * DI + kt + kc * 4];
            *(float4*)&ws[jj * 52 + kc * 4] = v;
        }
        __syncthreads();
        const float* wr0 = ws + lane * 52;
        #pragma unroll 4
        for (int kk = 0; kk < 48; kk += 4) {
            float4 xv0 = *(const float4*)&xs[(wv * 4 + 0) * 52 + kk];
            float4 xv1 = *(const float4*)&xs[(wv * 4 + 1) * 52 + kk];
            float4 xv2 = *(const float4*)&xs[(wv * 4 + 2) * 52 + kk];
            float4 xv3 = *(const float4*)&xs[(wv * 4 + 3) * 52 + kk];
            float4 wv4 = *(const float4*)&wr0[kk];
            acc[0] += xv0.x * wv4.x + xv0.y * wv4.y + xv0.z * wv4.z + xv0.w * wv4.w;
            acc[1] += xv1.x * wv4.x + xv1.y * wv4.y + xv1.z * wv4.z + xv1.w * wv4.w;
            acc[2] += xv2.x * wv4.x + xv2.y * wv4.y + xv2.z * wv4.z + xv2.w * wv4.w;
            acc[3] += xv3.x * wv4.x + xv3.y * wv4.y + xv3.z * wv4.z + xv3.w * wv4.w;
        }
        __syncthreads();
    }
    if (lane < 44) {
        #pragma unroll
        for (int t = 0; t < 4; t++) {
            sdbl[(wv * 4 + t) * 48 + lane] = acc[t];
            dbl[(size_t)(t0 + wv * 4 + t) * 44 + lane] = acc[t];
        }
    }
    const float* dwl = dtw + (size_t)layer * DI * DTR;
    for (int idx = threadIdx.x; idx < DI * DTR; idx += 256) {
        int d = idx / 12, rr = idx % 12;
        sdtw[d * 13 + rr] = dwl[idx];
    }
    __syncthreads();
    const float* dbb = dtbias + (size_t)layer * DI;
    for (int idx = threadIdx.x; idx < 16 * DI; idx += 256) {
        int tt = idx / DI, d = idx % DI;
        float a = dbb[d];
        const float* br = sdbl + tt * 48;
        const float* wr = sdtw + d * 13;
        #pragma unroll
        for (int rr = 0; rr < 12; rr++) a += br[rr] * wr[rr];
        dtbuf[(size_t)(t0 + tt) * DI + d] = softplusf(a);
    }
}

// ---------- chunked scan phase A: quad (4 lanes) per (b,c,d), 4 states/lane ----------
__global__ __launch_bounds__(256) void scanA(const float* __restrict__ dt,
                                             const float* __restrict__ xc,
                                             const float* __restrict__ dbl,
                                             const float* __restrict__ A_log,
                                             float* __restrict__ Pout,
                                             float* __restrict__ Hout,
                                             size_t aoff) {
    int Q = blockIdx.x * 64 + (threadIdx.x >> 2);
    int n0 = threadIdx.x & 3;
    int d = Q % DI;
    int bc = Q / DI;
    int b = bc / NC, c = bc % NC;
    float4 Al = *(const float4*)&A_log[aoff + (size_t)d * DS + n0 * 4];
    float A0 = -expf(Al.x), A1 = -expf(Al.y), A2 = -expf(Al.z), A3 = -expf(Al.w);
    float h0 = 0.f, h1 = 0.f, h2 = 0.f, h3 = 0.f;
    float P0 = 1.f, P1 = 1.f, P2 = 1.f, P3 = 1.f;
    int tbase = b * LL + c * LC;
    for (int l = 0; l < LC; l++) {
        size_t t = (size_t)tbase + l;
        float dtv = dt[t * DI + d];
        float xcv = xc[t * DI + d];
        float4 B4 = *(const float4*)&dbl[t * 44 + DTR + n0 * 4];
        float s = dtv * xcv;
        float e0 = __expf(dtv * A0), e1 = __expf(dtv * A1);
        float e2 = __expf(dtv * A2), e3 = __expf(dtv * A3);
        h0 = e0 * h0 + s * B4.x;  P0 *= e0;
        h1 = e1 * h1 + s * B4.y;  P1 *= e1;
        h2 = e2 * h2 + s * B4.z;  P2 *= e2;
        h3 = e3 * h3 + s * B4.w;  P3 *= e3;
    }
    size_t gi = (size_t)Q * 16 + n0 * 4;
    *(float4*)&Pout[gi] = make_float4(P0, P1, P2, P3);
    *(float4*)&Hout[gi] = make_float4(h0, h1, h2, h3);
}

// ---------- chunked scan phase C: fold prefix, replay, emit y. y aliases xc ----------
__global__ __launch_bounds__(256) void scanC(const float* __restrict__ dt,
                                             const float* xc,
                                             const float* __restrict__ dbl,
                                             const float* __restrict__ xz,
                                             const float* __restrict__ A_log,
                                             const float* __restrict__ Dskip,
                                             const float* __restrict__ Pin,
                                             const float* __restrict__ Hin,
                                             float* y,
                                             size_t aoff, size_t doff) {
    int Q = blockIdx.x * 64 + (threadIdx.x >> 2);
    int n0 = threadIdx.x & 3;
    int d = Q % DI;
    int bc = Q / DI;
    int b = bc / NC, c = bc % NC;
    float h0 = 0.f, h1 = 0.f, h2 = 0.f, h3 = 0.f;
    for (int cc = 0; cc < c; cc++) {
        size_t gi = ((size_t)(b * NC + cc) * DI + d) * 16 + n0 * 4;
        float4 P4 = *(const float4*)&Pin[gi];
        float4 H4 = *(const float4*)&Hin[gi];
        h0 = P4.x * h0 + H4.x;
        h1 = P4.y * h1 + H4.y;
        h2 = P4.z * h2 + H4.z;
        h3 = P4.w * h3 + H4.w;
    }
    float4 Al = *(const float4*)&A_log[aoff + (size_t)d * DS + n0 * 4];
    float A0 = -expf(Al.x), A1 = -expf(Al.y), A2 = -expf(Al.z), A3 = -expf(Al.w);
    float Dv = Dskip[doff + d];
    int tbase = b * LL + c * LC;
    for (int l = 0; l < LC; l++) {
        size_t t = (size_t)tbase + l;
        float dtv = dt[t * DI + d];
        float xcv = xc[t * DI + d];
        float4 B4 = *(const float4*)&dbl[t * 44 + DTR + n0 * 4];
        float4 C4 = *(const float4*)&dbl[t * 44 + DTR + DS + n0 * 4];
        float s = dtv * xcv;
        float e0 = __expf(dtv * A0), e1 = __expf(dtv * A1);
        float e2 = __expf(dtv * A2), e3 = __expf(dtv * A3);
        h0 = e0 * h0 + s * B4.x;
        h1 = e1 * h1 + s * B4.y;
        h2 = e2 * h2 + s * B4.z;
        h3 = e3 * h3 + s * B4.w;
        float p = h0 * C4.x + h1 * C4.y + h2 * C4.z + h3 * C4.w;
        p += __shfl_xor(p, 1);
        p += __shfl_xor(p, 2);
        if (n0 == 0) {
            float zg = xz[t * (2 * DI) + DI + d];
            y[t * DI + d] = (p + xcv * Dv) * siluf(zg);
        }
    }
}

// ---------- final: LN(residual + hidden) -> float32, 4 tokens/block ----------
__global__ __launch_bounds__(256) void final_kernel(const float* __restrict__ hidden,
                                                    const float* __restrict__ residual,
                                                    const float* __restrict__ w,
                                                    const float* __restrict__ bias,
                                                    float* __restrict__ out) {
    int t = blockIdx.x * 4 + (threadIdx.x >> 6);
    int lane = threadIdx.x & 63;
    size_t base = (size_t)t * DM;
    float a = residual[base + lane]       + hidden[base + lane];
    float b = residual[base + 64 + lane]  + hidden[base + 64 + lane];
    float c = residual[base + 128 + lane] + hidden[base + 128 + lane];
    float mu = wave_sum64(a + b + c) * (1.f / 192.f);
    float va = a - mu, vb = b - mu, vc = c - mu;
    float var = wave_sum64(va * va + vb * vb + vc * vc) * (1.f / 192.f);
    float inv = rsqrtf(var + EPSV);
    out[base + lane]       = va * inv * w[lane]       + bias[lane];
    out[base + 64 + lane]  = vb * inv * w[64 + lane]  + bias[64 + lane];
    out[base + 128 + lane] = vc * inv * w[128 + lane] + bias[128 + lane];
}

extern "C" void kernel_launch(void* const* d_in, const int* in_sizes, int n_in,
                              void* d_out, int out_size, void* d_ws, size_t ws_size,
                              hipStream_t stream) {
    const float* x_img   = (const float*)d_in[0];
    const float* z_img   = (const float*)d_in[1];
    const float* patch_w = (const float*)d_in[2];
    const float* patch_b = (const float*)d_in[3];
    const float* pos_x   = (const float*)d_in[4];
    const float* pos_z   = (const float*)d_in[5];
    const float* ln_w    = (const float*)d_in[6];
    const float* ln_b    = (const float*)d_in[7];
    const float* in_w    = (const float*)d_in[8];
    const float* conv_w  = (const float*)d_in[9];
    const float* conv_b  = (const float*)d_in[10];
    const float* xproj_w = (const float*)d_in[11];
    const float* dt_w    = (const float*)d_in[12];
    const float* dt_b    = (const float*)d_in[13];
    const float* A_log   = (const float*)d_in[14];
    const float* D_skip  = (const float*)d_in[15];
    const float* out_w   = (const float*)d_in[16];
    const float* fnorm_w = (const float*)d_in[17];
    const float* fnorm_b = (const float*)d_in[18];

    // ws layout (floats), ~48.0 MB total (<52 MB proven):
    float* hidden   = (float*)d_ws;                         // NT*DM
    float* residual = hidden   + (size_t)NT * DM;           // NT*DM
    float* xz       = residual + (size_t)NT * DM;           // NT*768
    float* xc       = xz       + (size_t)NT * 2 * DI;       // NT*DI
    float* dbl      = xc       + (size_t)NT * DI;           // NT*44
    float* dtbuf    = dbl      + (size_t)NT * 44;           // NT*DI
    float* scanP    = dtbuf    + (size_t)NT * DI;           // BB*NC*DI*16
    float* scanH    = scanP    + (size_t)BB * NC * DI * 16; // BB*NC*DI*16
    float* yb       = xc;       // alias (read-before-write per step)
    float* resalt   = (float*)d_out;  // residual ping-pong partner (dead until final)

    // z-first concat: z tokens 0..63, x tokens 64..319 (one combined launch)
    {
        dim3 gp((BB * NX + BB * NZ) / 32, 3);   // (160, 3)
        patch_rt2<<<gp, 128, 0, stream>>>(x_img, z_img, patch_w, patch_b,
                                          pos_x, pos_z, hidden);
    }

    const int scan_blocks = BB * NC * DI / 64;   // 960 (64 quads/block)
    for (int i = 0; i < DEPTH; i++) {
        // residual parity: layer i reads res_{i-1}, writes res_i.
        // even i -> resalt (d_out), odd i -> residual. Layer 23 -> residual.
        const float* resin = (i % 2) ? resalt : residual;
        float* resout      = (i % 2) ? residual : resalt;
        {
            dim3 g(NT / 32, 6);   // 960 blocks, 128 cols each
            ln_gemm<<<g, 256, 0, stream>>>(
                hidden, resin, resout, ln_w, ln_b, (size_t)i * DM,
                in_w, (size_t)i * 768 * 192, xz, i == 0 ? 1 : 0);
        }
        xpd_kernel<<<NT / 16, 256, 0, stream>>>(
            xz, conv_w, conv_b, xproj_w, dt_w, dt_b, xc, dbl, dtbuf, i);
        scanA<<<scan_blocks, 256, 0, stream>>>(
            dtbuf, xc, dbl, A_log, scanP, scanH, (size_t)i * DI * DS);
        scanC<<<scan_blocks, 256, 0, stream>>>(
            dtbuf, xc, dbl, xz, A_log, D_skip, scanP, scanH, yb,
            (size_t)i * DI * DS, (size_t)i * DI);
        {
            dim3 g(NT / 32, 3);   // 480 blocks, 64 cols each
            gemm_rt2<384, 96><<<g, 128, 0, stream>>>(
                yb, out_w, (size_t)i * 192 * 384, hidden, 192);
        }
    }

    final_kernel<<<NT / 4, 256, 0, stream>>>(hidden, residual, fnorm_w, fnorm_b,
                                             (float*)d_out);
}

// Round 7
// 4037.653 us; speedup vs baseline: 1.1257x; 1.1257x over previous
//
#include <hip/hip_runtime.h>
#include <hip/hip_bf16.h>

#define BB 16
#define DEPTH 24
#define DM 192
#define DI 384
#define DS 16
#define DC 4
#define DTR 12
#define LL 320
#define NX 256
#define NZ 64
#define NT (BB * LL)
#define NC 10         // scan chunks
#define LC 32         // chunk length
#define EPSV 1e-5f

__device__ inline float siluf(float x) { return x / (1.f + __expf(-x)); }
__device__ inline float softplusf(float x) {
    return (x > 20.f) ? x : log1pf(expf(x));
}
__device__ inline float wave_sum64(float v) {
    #pragma unroll
    for (int o = 32; o > 0; o >>= 1) v += __shfl_xor(v, o);
    return v;
}

// ---------- add + LN prenorm: one wave per token, 4 tokens/block ----------
// first=1: residual_in treated as zero (layer 0), still writes residual.
__global__ __launch_bounds__(256) void addnorm_kernel(const float* hidden,
                                                      float* __restrict__ residual,
                                                      float* hn,
                                                      const float* __restrict__ w,
                                                      const float* __restrict__ bias,
                                                      size_t off, int first) {
    int t = blockIdx.x * 4 + (threadIdx.x >> 6);
    int lane = threadIdx.x & 63;
    size_t base = (size_t)t * DM;
    float a = hidden[base + lane];
    float b = hidden[base + 64 + lane];
    float c = hidden[base + 128 + lane];
    if (!first) {
        a += residual[base + lane];
        b += residual[base + 64 + lane];
        c += residual[base + 128 + lane];
    }
    residual[base + lane] = a;
    residual[base + 64 + lane] = b;
    residual[base + 128 + lane] = c;
    float mu = wave_sum64(a + b + c) * (1.f / 192.f);
    float va = a - mu, vb = b - mu, vc = c - mu;
    float var = wave_sum64(va * va + vb * vb + vc * vc) * (1.f / 192.f);
    float inv = rsqrtf(var + EPSV);
    hn[base + lane]       = va * inv * w[off + lane]       + bias[off + lane];
    hn[base + 64 + lane]  = vb * inv * w[off + 64 + lane]  + bias[off + 64 + lane];
    hn[base + 128 + lane] = vc * inv * w[off + 128 + lane] + bias[off + 128 + lane];
}

// ---------- register-tiled GEMM, b128 weight reads ----------
// Block: 256 thr = 4 waves; wave owns 8 tokens; lane owns NO cols (stride 64).
// xs rows: broadcast reads (conflict-free). ws rows stride KT+4 (==4 mod 32
// for KT=48/96): b128 bank-start covers all 32 banks per 8 rows.
template<int K, int KT, int NO>
__global__ __launch_bounds__(256) void gemm_rt(const float* __restrict__ x,
                                               const float* __restrict__ w,
                                               size_t woff,
                                               float* __restrict__ out, int N) {
    constexpr int NCOL = 64 * NO;
    constexpr int KC = KT / 4;
    __shared__ float xs[32][KT + 4];
    __shared__ float ws[NCOL][KT + 4];
    int t0 = blockIdx.x * 32;
    int j0 = blockIdx.y * NCOL;
    int lane = threadIdx.x & 63;
    int wv = threadIdx.x >> 6;
    float acc[8][NO];
    #pragma unroll
    for (int t = 0; t < 8; t++)
        #pragma unroll
        for (int o = 0; o < NO; o++) acc[t][o] = 0.f;

    for (int kt = 0; kt < K; kt += KT) {
        for (int idx = threadIdx.x; idx < 32 * KC; idx += 256) {
            int tt = idx / KC, kc = idx % KC;
            float4 v = *(const float4*)&x[(size_t)(t0 + tt) * K + kt + kc * 4];
            *(float4*)&xs[tt][kc * 4] = v;
        }
        for (int idx = threadIdx.x; idx < NCOL * KC; idx += 256) {
            int jj = idx / KC, kc = idx % KC;
            float4 v = *(const float4*)&w[woff + (size_t)(j0 + jj) * K + kt + kc * 4];
            *(float4*)&ws[jj][kc * 4] = v;
        }
        __syncthreads();
        #pragma unroll 2
        for (int kk = 0; kk < KT; kk += 4) {
            float4 xv[8];
            #pragma unroll
            for (int t = 0; t < 8; t++)
                xv[t] = *(const float4*)&xs[wv * 8 + t][kk];
            #pragma unroll
            for (int o = 0; o < NO; o++) {
                float4 wv4 = *(const float4*)&ws[lane + 64 * o][kk];
                #pragma unroll
                for (int t = 0; t < 8; t++)
                    acc[t][o] += xv[t].x * wv4.x + xv[t].y * wv4.y
                               + xv[t].z * wv4.z + xv[t].w * wv4.w;
            }
        }
        __syncthreads();
    }
    #pragma unroll
    for (int t = 0; t < 8; t++)
        #pragma unroll
        for (int o = 0; o < NO; o++)
            out[(size_t)(t0 + wv * 8 + t) * N + j0 + lane + 64 * o] = acc[t][o];
}

// ---------- patch embed (both images, one launch). KT=96, b128 reads, 256 thr ----------
// grid: ((BB*NX + BB*NZ)/32 = 160, 3). blocks 0..127 -> x_img, 128..159 -> z_img
__global__ __launch_bounds__(256) void patch_rt(const float* __restrict__ x_img,
                                                const float* __restrict__ z_img,
                                                const float* __restrict__ w,
                                                const float* __restrict__ bias,
                                                const float* __restrict__ pos_x,
                                                const float* __restrict__ pos_z,
                                                float* __restrict__ hidden) {
    __shared__ float xs[32][100];
    __shared__ float ws[64][100];
    bool isx = blockIdx.x < (BB * NX / 32);
    const float* img = isx ? x_img : z_img;
    const float* pos = isx ? pos_x : pos_z;
    int side = isx ? 16 : 8;
    int tok_off = isx ? NZ : 0;
    int ntok = side * side;
    int pt0 = (isx ? blockIdx.x : blockIdx.x - BB * NX / 32) * 32;
    int j0 = blockIdx.y * 64;
    int S = side * 16;
    int lane = threadIdx.x & 63;
    int wv = threadIdx.x >> 6;
    float acc[8];
    #pragma unroll
    for (int t = 0; t < 8; t++) acc[t] = 0.f;

    for (int kt = 0; kt < 768; kt += 96) {
        for (int idx = threadIdx.x; idx < 32 * 24; idx += 256) {
            int tt = idx / 24, kc = idx % 24;
            int k = kt + kc * 4;
            int c = k >> 8, p = k & 255, pi = p >> 4, pj = p & 15;
            int patch = pt0 + tt;
            int b = patch / ntok, t = patch % ntok;
            int ph = t / side, pw = t % side;
            float4 v = *(const float4*)&img[((size_t)(b * 3 + c) * S + ph * 16 + pi) * S
                                            + pw * 16 + pj];
            *(float4*)&xs[tt][kc * 4] = v;
        }
        for (int idx = threadIdx.x; idx < 64 * 24; idx += 256) {
            int jj = idx / 24, kc = idx % 24;
            float4 v = *(const float4*)&w[(size_t)(j0 + jj) * 768 + kt + kc * 4];
            *(float4*)&ws[jj][kc * 4] = v;
        }
        __syncthreads();
        #pragma unroll 2
        for (int kk = 0; kk < 96; kk += 4) {
            float4 xv[8];
            #pragma unroll
            for (int t = 0; t < 8; t++)
                xv[t] = *(const float4*)&xs[wv * 8 + t][kk];
            float4 wv4 = *(const float4*)&ws[lane][kk];
            #pragma unroll
            for (int t = 0; t < 8; t++)
                acc[t] += xv[t].x * wv4.x + xv[t].y * wv4.y
                        + xv[t].z * wv4.z + xv[t].w * wv4.w;
        }
        __syncthreads();
    }
    float bj = bias[j0 + lane];
    #pragma unroll
    for (int t = 0; t < 8; t++) {
        int patch = pt0 + wv * 8 + t;
        int b = patch / ntok, tk = patch % ntok;
        hidden[((size_t)b * LL + tok_off + tk) * DM + j0 + lane] =
            acc[t] + bj + pos[(size_t)tk * DM + j0 + lane];
    }
}

// ---------- fused conv+silu -> x_proj (reg-tiled) -> dt_proj. block = 16 tokens ----------
__global__ __launch_bounds__(256) void xpd_kernel(const float* __restrict__ xz,
                                                  const float* __restrict__ cw,
                                                  const float* __restrict__ cb,
                                                  const float* __restrict__ xpw,
                                                  const float* __restrict__ dtw,
                                                  const float* __restrict__ dtbias,
                                                  float* __restrict__ xc,
                                                  float* __restrict__ dbl,
                                                  float* __restrict__ dtbuf,
                                                  int layer) {
    __shared__ float smem[5760];
    float* xs   = smem;          // [16][52]
    float* ws   = smem + 832;    // [64][52]
    float* sdbl = smem;          // [16][48]
    float* sdtw = smem + 768;    // [384][13] -> bank (13d+r)%32, 2-way free

    int t0 = blockIdx.x * 16;
    int l0 = t0 % LL;
    int lane = threadIdx.x & 63;
    int wv = threadIdx.x >> 6;
    const float* cwl = cw  + (size_t)layer * DI * DC;
    const float* cbl = cb  + (size_t)layer * DI;
    const float* xpl = xpw + (size_t)layer * 44 * DI;
    float acc[4] = {0.f, 0.f, 0.f, 0.f};

    for (int kt = 0; kt < DI; kt += 48) {
        for (int idx = threadIdx.x; idx < 16 * 48; idx += 256) {
            int tt = idx / 48, kk = idx % 48;
            int d = kt + kk;
            float a = cbl[d];
            #pragma unroll
            for (int rr = 0; rr < 4; rr++) {
                int l = l0 + tt - 3 + rr;
                float v = (l >= 0) ? xz[(size_t)(t0 + tt - 3 + rr) * 768 + d] : 0.f;
                a += cwl[d * 4 + rr] * v;
            }
            a = siluf(a);
            xs[tt * 52 + kk] = a;
            xc[(size_t)(t0 + tt) * DI + d] = a;
        }
        for (int idx = threadIdx.x; idx < 64 * 12; idx += 256) {
            int jj = idx / 12, kc = idx % 12;
            float4 v = make_float4(0.f, 0.f, 0.f, 0.f);
            if (jj < 44)
                v = *(const float4*)&xpl[(size_t)jj * DI + kt + kc * 4];
            *(float4*)&ws[jj * 52 + kc * 4] = v;
        }
        __syncthreads();
        const float* wr0 = ws + lane * 52;
        #pragma unroll 4
        for (int kk = 0; kk < 48; kk += 4) {
            float4 xv0 = *(const float4*)&xs[(wv * 4 + 0) * 52 + kk];
            float4 xv1 = *(const float4*)&xs[(wv * 4 + 1) * 52 + kk];
            float4 xv2 = *(const float4*)&xs[(wv * 4 + 2) * 52 + kk];
            float4 xv3 = *(const float4*)&xs[(wv * 4 + 3) * 52 + kk];
            float4 wv4 = *(const float4*)&wr0[kk];
            acc[0] += xv0.x * wv4.x + xv0.y * wv4.y + xv0.z * wv4.z + xv0.w * wv4.w;
            acc[1] += xv1.x * wv4.x + xv1.y * wv4.y + xv1.z * wv4.z + xv1.w * wv4.w;
            acc[2] += xv2.x * wv4.x + xv2.y * wv4.y + xv2.z * wv4.z + xv2.w * wv4.w;
            acc[3] += xv3.x * wv4.x + xv3.y * wv4.y + xv3.z * wv4.z + xv3.w * wv4.w;
        }
        __syncthreads();
    }
    if (lane < 44) {
        #pragma unroll
        for (int t = 0; t < 4; t++) {
            sdbl[(wv * 4 + t) * 48 + lane] = acc[t];
            dbl[(size_t)(t0 + wv * 4 + t) * 44 + lane] = acc[t];
        }
    }
    const float* dwl = dtw + (size_t)layer * DI * DTR;
    for (int idx = threadIdx.x; idx < DI * DTR; idx += 256) {
        int d = idx / 12, rr = idx % 12;
        sdtw[d * 13 + rr] = dwl[idx];
    }
    __syncthreads();
    const float* dbb = dtbias + (size_t)layer * DI;
    for (int idx = threadIdx.x; idx < 16 * DI; idx += 256) {
        int tt = idx / DI, d = idx % DI;
        float a = dbb[d];
        const float* br = sdbl + tt * 48;
        const float* wr = sdtw + d * 13;
        #pragma unroll
        for (int rr = 0; rr < 12; rr++) a += br[rr] * wr[rr];
        dtbuf[(size_t)(t0 + tt) * DI + d] = softplusf(a);
    }
}

// ---------- chunked scan phase A: quad (4 lanes) per (b,c,d), 4 states/lane ----------
__global__ __launch_bounds__(256) void scanA(const float* __restrict__ dt,
                                             const float* __restrict__ xc,
                                             const float* __restrict__ dbl,
                                             const float* __restrict__ A_log,
                                             float* __restrict__ Pout,
                                             float* __restrict__ Hout,
                                             size_t aoff) {
    int Q = blockIdx.x * 64 + (threadIdx.x >> 2);
    int n0 = threadIdx.x & 3;
    int d = Q % DI;
    int bc = Q / DI;
    int b = bc / NC, c = bc % NC;
    float4 Al = *(const float4*)&A_log[aoff + (size_t)d * DS + n0 * 4];
    float A0 = -expf(Al.x), A1 = -expf(Al.y), A2 = -expf(Al.z), A3 = -expf(Al.w);
    float h0 = 0.f, h1 = 0.f, h2 = 0.f, h3 = 0.f;
    float P0 = 1.f, P1 = 1.f, P2 = 1.f, P3 = 1.f;
    int tbase = b * LL + c * LC;
    for (int l = 0; l < LC; l++) {
        size_t t = (size_t)tbase + l;
        float dtv = dt[t * DI + d];
        float xcv = xc[t * DI + d];
        float4 B4 = *(const float4*)&dbl[t * 44 + DTR + n0 * 4];
        float s = dtv * xcv;
        float e0 = __expf(dtv * A0), e1 = __expf(dtv * A1);
        float e2 = __expf(dtv * A2), e3 = __expf(dtv * A3);
        h0 = e0 * h0 + s * B4.x;  P0 *= e0;
        h1 = e1 * h1 + s * B4.y;  P1 *= e1;
        h2 = e2 * h2 + s * B4.z;  P2 *= e2;
        h3 = e3 * h3 + s * B4.w;  P3 *= e3;
    }
    size_t gi = (size_t)Q * 16 + n0 * 4;
    *(float4*)&Pout[gi] = make_float4(P0, P1, P2, P3);
    *(float4*)&Hout[gi] = make_float4(h0, h1, h2, h3);
}

// ---------- chunked scan phase C: fold prefix, replay, emit y. y aliases xc ----------
__global__ __launch_bounds__(256) void scanC(const float* __restrict__ dt,
                                             const float* xc,
                                             const float* __restrict__ dbl,
                                             const float* __restrict__ xz,
                                             const float* __restrict__ A_log,
                                             const float* __restrict__ Dskip,
                                             const float* __restrict__ Pin,
                                             const float* __restrict__ Hin,
                                             float* y,
                                             size_t aoff, size_t doff) {
    int Q = blockIdx.x * 64 + (threadIdx.x >> 2);
    int n0 = threadIdx.x & 3;
    int d = Q % DI;
    int bc = Q / DI;
    int b = bc / NC, c = bc % NC;
    float h0 = 0.f, h1 = 0.f, h2 = 0.f, h3 = 0.f;
    for (int cc = 0; cc < c; cc++) {
        size_t gi = ((size_t)(b * NC + cc) * DI + d) * 16 + n0 * 4;
        float4 P4 = *(const float4*)&Pin[gi];
        float4 H4 = *(const float4*)&Hin[gi];
        h0 = P4.x * h0 + H4.x;
        h1 = P4.y * h1 + H4.y;
        h2 = P4.z * h2 + H4.z;
        h3 = P4.w * h3 + H4.w;
    }
    float4 Al = *(const float4*)&A_log[aoff + (size_t)d * DS + n0 * 4];
    float A0 = -expf(Al.x), A1 = -expf(Al.y), A2 = -expf(Al.z), A3 = -expf(Al.w);
    float Dv = Dskip[doff + d];
    int tbase = b * LL + c * LC;
    for (int l = 0; l < LC; l++) {
        size_t t = (size_t)tbase + l;
        float dtv = dt[t * DI + d];
        float xcv = xc[t * DI + d];
        float4 B4 = *(const float4*)&dbl[t * 44 + DTR + n0 * 4];
        float4 C4 = *(const float4*)&dbl[t * 44 + DTR + DS + n0 * 4];
        float s = dtv * xcv;
        float e0 = __expf(dtv * A0), e1 = __expf(dtv * A1);
        float e2 = __expf(dtv * A2), e3 = __expf(dtv * A3);
        h0 = e0 * h0 + s * B4.x;
        h1 = e1 * h1 + s * B4.y;
        h2 = e2 * h2 + s * B4.z;
        h3 = e3 * h3 + s * B4.w;
        float p = h0 * C4.x + h1 * C4.y + h2 * C4.z + h3 * C4.w;
        p += __shfl_xor(p, 1);
        p += __shfl_xor(p, 2);
        if (n0 == 0) {
            float zg = xz[t * (2 * DI) + DI + d];
            y[t * DI + d] = (p + xcv * Dv) * siluf(zg);
        }
    }
}

// ---------- final: LN(residual + hidden) -> float32, 4 tokens/block ----------
__global__ __launch_bounds__(256) void final_kernel(const float* __restrict__ hidden,
                                                    const float* __restrict__ residual,
                                                    const float* __restrict__ w,
                                                    const float* __restrict__ bias,
                                                    float* __restrict__ out) {
    int t = blockIdx.x * 4 + (threadIdx.x >> 6);
    int lane = threadIdx.x & 63;
    size_t base = (size_t)t * DM;
    float a = residual[base + lane]       + hidden[base + lane];
    float b = residual[base + 64 + lane]  + hidden[base + 64 + lane];
    float c = residual[base + 128 + lane] + hidden[base + 128 + lane];
    float mu = wave_sum64(a + b + c) * (1.f / 192.f);
    float va = a - mu, vb = b - mu, vc = c - mu;
    float var = wave_sum64(va * va + vb * vb + vc * vc) * (1.f / 192.f);
    float inv = rsqrtf(var + EPSV);
    out[base + lane]       = va * inv * w[lane]       + bias[lane];
    out[base + 64 + lane]  = vb * inv * w[64 + lane]  + bias[64 + lane];
    out[base + 128 + lane] = vc * inv * w[128 + lane] + bias[128 + lane];
}

extern "C" void kernel_launch(void* const* d_in, const int* in_sizes, int n_in,
                              void* d_out, int out_size, void* d_ws, size_t ws_size,
                              hipStream_t stream) {
    const float* x_img   = (const float*)d_in[0];
    const float* z_img   = (const float*)d_in[1];
    const float* patch_w = (const float*)d_in[2];
    const float* patch_b = (const float*)d_in[3];
    const float* pos_x   = (const float*)d_in[4];
    const float* pos_z   = (const float*)d_in[5];
    const float* ln_w    = (const float*)d_in[6];
    const float* ln_b    = (const float*)d_in[7];
    const float* in_w    = (const float*)d_in[8];
    const float* conv_w  = (const float*)d_in[9];
    const float* conv_b  = (const float*)d_in[10];
    const float* xproj_w = (const float*)d_in[11];
    const float* dt_w    = (const float*)d_in[12];
    const float* dt_b    = (const float*)d_in[13];
    const float* A_log   = (const float*)d_in[14];
    const float* D_skip  = (const float*)d_in[15];
    const float* out_w   = (const float*)d_in[16];
    const float* fnorm_w = (const float*)d_in[17];
    const float* fnorm_b = (const float*)d_in[18];

    // ws layout (floats), ~48.0 MB total (<52 MB proven):
    float* hidden   = (float*)d_ws;                         // NT*DM
    float* residual = hidden   + (size_t)NT * DM;           // NT*DM
    float* xz       = residual + (size_t)NT * DM;           // NT*768
    float* xc       = xz       + (size_t)NT * 2 * DI;       // NT*DI
    float* dbl      = xc       + (size_t)NT * DI;           // NT*44
    float* dtbuf    = dbl      + (size_t)NT * 44;           // NT*DI
    float* scanP    = dtbuf    + (size_t)NT * DI;           // BB*NC*DI*16
    float* scanH    = scanP    + (size_t)BB * NC * DI * 16; // BB*NC*DI*16
    float* hn       = hidden;   // alias (read-before-write per thread)
    float* yb       = xc;       // alias (read-before-write per step)

    // z-first concat: z tokens 0..63, x tokens 64..319 (one combined launch)
    {
        dim3 gp((BB * NX + BB * NZ) / 32, 3);   // (160, 3)
        patch_rt<<<gp, 256, 0, stream>>>(x_img, z_img, patch_w, patch_b,
                                         pos_x, pos_z, hidden);
    }

    const int scan_blocks = BB * NC * DI / 64;   // 960 (64 quads/block)
    for (int i = 0; i < DEPTH; i++) {
        addnorm_kernel<<<NT / 4, 256, 0, stream>>>(
            hidden, residual, hn, ln_w, ln_b, (size_t)i * DM, i == 0 ? 1 : 0);
        {
            dim3 g(NT / 32, 6);   // 960 blocks, NCOL=128
            gemm_rt<192, 48, 2><<<g, 256, 0, stream>>>(
                hn, in_w, (size_t)i * 768 * 192, xz, 768);
        }
        xpd_kernel<<<NT / 16, 256, 0, stream>>>(
            xz, conv_w, conv_b, xproj_w, dt_w, dt_b, xc, dbl, dtbuf, i);
        scanA<<<scan_blocks, 256, 0, stream>>>(
            dtbuf, xc, dbl, A_log, scanP, scanH, (size_t)i * DI * DS);
        scanC<<<scan_blocks, 256, 0, stream>>>(
            dtbuf, xc, dbl, xz, A_log, D_skip, scanP, scanH, yb,
            (size_t)i * DI * DS, (size_t)i * DI);
        {
            dim3 g(NT / 32, 3);   // 480 blocks, NCOL=64, KT=96 (4 stage rounds)
            gemm_rt<384, 96, 1><<<g, 256, 0, stream>>>(
                yb, out_w, (size_t)i * 192 * 384, hidden, 192);
        }
    }

    final_kernel<<<NT / 4, 256, 0, stream>>>(hidden, residual, fnorm_w, fnorm_b,
                                             (float*)d_out);
}